// Round 6
// baseline (288.953 us; speedup 1.0000x reference)
//
#include <hip/hip_runtime.h>
#include <math.h>

#define D_STATE 16
#define DT_RANK 6
constexpr int Bc = 2, Cc = 96, Hc = 128, Wcn = 128;
constexpr int DI = 192;       // d_inner
constexpr int Lq = 4096;      // 64*64 per quadrant
constexpr int CH = 32;        // scan chunk length
constexpr int NCH = Lq / CH;  // 128 chunks

// ---------------- DCT matrix build ------------------------------------------
__global__ void k_dct_mat(float* __restrict__ M, float* __restrict__ MT) {
    int i = blockIdx.x * blockDim.x + threadIdx.x; // 16384
    int n = i >> 7, k = i & 127;
    double v = cos(3.14159265358979323846 * (2.0 * k + 1.0) * n / 256.0) * sqrt(2.0 / 128.0);
    if (n == 0) v *= 0.70710678118654752440;
    M[n * 128 + k]  = (float)v;
    MT[k * 128 + n] = (float)v;
}

// ---------------- cosine-similarity mask: keep plane only -------------------
__global__ void k_mask2(const float* __restrict__ x, float* __restrict__ keep) {
    int b = blockIdx.y, h = blockIdx.x, w = threadIdx.x;
    const float* xb = x + (size_t)b * Cc * Hc * Wcn;
    float dot = 0.f, ss = 0.f, cs = 0.f;
    for (int c = 0; c < Cc; c++) {
        float xv = xb[(size_t)(c * Hc + h) * Wcn + w];
        float cv = xb[(size_t)(c * Hc + 64) * Wcn + 64];
        dot += xv * cv; ss += xv * xv; cs += cv * cv;
    }
    float sim = dot / (sqrtf(cs) * sqrtf(ss) + 1e-6f);
    keep[(size_t)b * 16384 + h * 128 + w] = (sim >= 0.7f) ? 1.0f : 0.0f;
}

// ---------------- tiled 128-GEMM: D[r][n] = sum_j L[r][j]R[j][n] ------------
// tile 64r x 128n, K=128 split 2x64; optional mask on R (keep[b][j][n]).
__global__ void k_g128(const float* __restrict__ L, size_t lb,
                       const float* __restrict__ R, size_t rb,
                       float* __restrict__ D, const float* __restrict__ mask) {
    __shared__ float Ls[64][68];
    __shared__ float Rs[64][132];
    int bc = blockIdx.x;
    int r0 = blockIdx.y * 64;
    const float* Lp = L + lb * bc;
    const float* Rp = R + rb * bc;
    const float* mp = mask ? mask + (size_t)(bc / 96) * 16384 : nullptr;
    float* Dq = D + (size_t)bc * 16384;
    int tid = threadIdx.x, tx = tid & 15, ty = tid >> 4;
    float acc[4][8] = {};
    for (int ks = 0; ks < 2; ks++) {
        __syncthreads();
        #pragma unroll
        for (int i = 0; i < 4; i++) {
            int idx = i * 256 + tid;          // 1024 = 64 rows x 16 f4
            int row = idx >> 4, quad = idx & 15;
            *(float4*)&Ls[row][quad * 4] =
                *(const float4*)(Lp + (size_t)(r0 + row) * 128 + ks * 64 + quad * 4);
        }
        #pragma unroll
        for (int i = 0; i < 8; i++) {
            int idx = i * 256 + tid;          // 2048 = 64 rows x 32 f4
            int row = idx >> 5, quad = idx & 31;
            float4 v = *(const float4*)(Rp + (size_t)(ks * 64 + row) * 128 + quad * 4);
            if (mp) {
                float4 m4 = *(const float4*)(mp + (size_t)(ks * 64 + row) * 128 + quad * 4);
                v.x *= m4.x; v.y *= m4.y; v.z *= m4.z; v.w *= m4.w;
            }
            *(float4*)&Rs[row][quad * 4] = v;
        }
        __syncthreads();
        #pragma unroll 4
        for (int j = 0; j < 64; j++) {
            float a0 = Ls[ty][j], a1 = Ls[ty + 16][j], a2 = Ls[ty + 32][j], a3 = Ls[ty + 48][j];
            float4 b0 = *(float4*)&Rs[j][tx * 4];
            float4 b1 = *(float4*)&Rs[j][64 + tx * 4];
            acc[0][0] += a0 * b0.x; acc[0][1] += a0 * b0.y; acc[0][2] += a0 * b0.z; acc[0][3] += a0 * b0.w;
            acc[0][4] += a0 * b1.x; acc[0][5] += a0 * b1.y; acc[0][6] += a0 * b1.z; acc[0][7] += a0 * b1.w;
            acc[1][0] += a1 * b0.x; acc[1][1] += a1 * b0.y; acc[1][2] += a1 * b0.z; acc[1][3] += a1 * b0.w;
            acc[1][4] += a1 * b1.x; acc[1][5] += a1 * b1.y; acc[1][6] += a1 * b1.z; acc[1][7] += a1 * b1.w;
            acc[2][0] += a2 * b0.x; acc[2][1] += a2 * b0.y; acc[2][2] += a2 * b0.z; acc[2][3] += a2 * b0.w;
            acc[2][4] += a2 * b1.x; acc[2][5] += a2 * b1.y; acc[2][6] += a2 * b1.z; acc[2][7] += a2 * b1.w;
            acc[3][0] += a3 * b0.x; acc[3][1] += a3 * b0.y; acc[3][2] += a3 * b0.z; acc[3][3] += a3 * b0.w;
            acc[3][4] += a3 * b1.x; acc[3][5] += a3 * b1.y; acc[3][6] += a3 * b1.z; acc[3][7] += a3 * b1.w;
        }
    }
    #pragma unroll
    for (int i = 0; i < 4; i++) {
        *(float4*)(Dq + (size_t)(r0 + ty + 16 * i) * 128 + tx * 4) =
            make_float4(acc[i][0], acc[i][1], acc[i][2], acc[i][3]);
        *(float4*)(Dq + (size_t)(r0 + ty + 16 * i) * 128 + 64 + tx * 4) =
            make_float4(acc[i][4], acc[i][5], acc[i][6], acc[i][7]);
    }
}

// ---------------- LayerNorm + quadrant pack: xn[qb][c][l] -------------------
__global__ void k_ln_pack(const float* __restrict__ xd, const float* __restrict__ lnw,
                          const float* __restrict__ lnb, float* __restrict__ xn) {
    __shared__ float lws[96], lbs[96];
    int h = blockIdx.x, b = blockIdx.y, w = threadIdx.x;
    if (w < 96) { lws[w] = lnw[w]; lbs[w] = lnb[w]; }
    __syncthreads();
    const float* p = xd + ((size_t)b * Cc * Hc + h) * Wcn + w;
    float v[96];
    float mu = 0.f;
    #pragma unroll
    for (int c = 0; c < 96; c++) { v[c] = p[(size_t)c * 16384]; mu += v[c]; }
    mu *= (1.f / 96.f);
    float var = 0.f;
    #pragma unroll
    for (int c = 0; c < 96; c++) { float d = v[c] - mu; var += d * d; }
    float inv = rsqrtf(var * (1.f / 96.f) + 1e-5f);
    int q = (h >> 6) * 2 + (w >> 6);
    int qb = q * 2 + b;
    int l = (h & 63) * 64 + (w & 63);
    float* o = xn + (size_t)qb * Cc * Lq + l;
    #pragma unroll
    for (int c = 0; c < 96; c++)
        o[(size_t)c * Lq] = (v[c] - mu) * inv * lws[c] + lbs[c];
}

// ---------------- in-projection GEMM: xz[qb][e][l], e in [0,384) ------------
__global__ void k_inproj_g(const float* __restrict__ xn, const float* __restrict__ in_w,
                           float* __restrict__ xz) {
    __shared__ float Ws[64][52];     // [e][k-chunk 48]
    __shared__ float Xs[48][132];    // [k][l-tile 128]
    int lt = blockIdx.x, et = blockIdx.y, qb = blockIdx.z;
    int q = qb >> 1;
    int tid = threadIdx.x, tx = tid & 15, ty = tid >> 4;
    int l0 = lt * 128;
    float acc[4][8] = {};
    for (int ks = 0; ks < 2; ks++) {
        __syncthreads();
        #pragma unroll
        for (int i = 0; i < 3; i++) {
            int idx = i * 256 + tid;         // 768 = 64 rows x 12 f4
            int row = idx / 12, q4 = idx % 12;
            *(float4*)&Ws[row][q4 * 4] =
                *(const float4*)(in_w + ((size_t)(q * 384 + et * 64 + row)) * 96 + ks * 48 + q4 * 4);
        }
        #pragma unroll
        for (int i = 0; i < 6; i++) {
            int idx = i * 256 + tid;         // 1536 = 48 rows x 32 f4
            int row = idx >> 5, quad = idx & 31;
            *(float4*)&Xs[row][quad * 4] =
                *(const float4*)(xn + ((size_t)qb * Cc + ks * 48 + row) * Lq + l0 + quad * 4);
        }
        __syncthreads();
        #pragma unroll 4
        for (int k = 0; k < 48; k++) {
            float a0 = Ws[ty][k], a1 = Ws[ty + 16][k], a2 = Ws[ty + 32][k], a3 = Ws[ty + 48][k];
            float4 b0 = *(float4*)&Xs[k][tx * 4];
            float4 b1 = *(float4*)&Xs[k][64 + tx * 4];
            acc[0][0] += a0 * b0.x; acc[0][1] += a0 * b0.y; acc[0][2] += a0 * b0.z; acc[0][3] += a0 * b0.w;
            acc[0][4] += a0 * b1.x; acc[0][5] += a0 * b1.y; acc[0][6] += a0 * b1.z; acc[0][7] += a0 * b1.w;
            acc[1][0] += a1 * b0.x; acc[1][1] += a1 * b0.y; acc[1][2] += a1 * b0.z; acc[1][3] += a1 * b0.w;
            acc[1][4] += a1 * b1.x; acc[1][5] += a1 * b1.y; acc[1][6] += a1 * b1.z; acc[1][7] += a1 * b1.w;
            acc[2][0] += a2 * b0.x; acc[2][1] += a2 * b0.y; acc[2][2] += a2 * b0.z; acc[2][3] += a2 * b0.w;
            acc[2][4] += a2 * b1.x; acc[2][5] += a2 * b1.y; acc[2][6] += a2 * b1.z; acc[2][7] += a2 * b1.w;
            acc[3][0] += a3 * b0.x; acc[3][1] += a3 * b0.y; acc[3][2] += a3 * b0.z; acc[3][3] += a3 * b0.w;
            acc[3][4] += a3 * b1.x; acc[3][5] += a3 * b1.y; acc[3][6] += a3 * b1.z; acc[3][7] += a3 * b1.w;
        }
    }
    #pragma unroll
    for (int i = 0; i < 4; i++) {
        size_t rb = ((size_t)qb * 384 + et * 64 + ty + 16 * i) * Lq + l0;
        *(float4*)(xz + rb + tx * 4) = make_float4(acc[i][0], acc[i][1], acc[i][2], acc[i][3]);
        *(float4*)(xz + rb + 64 + tx * 4) = make_float4(acc[i][4], acc[i][5], acc[i][6], acc[i][7]);
    }
}

// ---------------- conv/silu (d<192) or silu(z) (d>=192); transpose to [l][d]
__global__ void k_conv(const float* __restrict__ xz, const float* __restrict__ cw,
                       const float* __restrict__ cb, float* __restrict__ xi,
                       float* __restrict__ szt) {
    __shared__ float xs[64][68];
    int lt = blockIdx.x, dt = blockIdx.y;
    int qb = blockIdx.z, q = qb >> 1;
    int tid = threadIdx.x;
    int l0 = lt * 64, d0 = dt * 64;
    bool isz = dt >= 3;
    if (!isz) {
        #pragma unroll
        for (int it = 0; it < 5; it++) {
            int idx = it * 256 + tid;        // 1088 = 64 rows x 17 f4 (4-col halo)
            if (idx < 1088) {
                int row = idx / 17, q4 = idx % 17;
                if (l0 == 0 && q4 == 0)
                    *(float4*)&xs[row][0] = make_float4(0.f, 0.f, 0.f, 0.f);
                else
                    *(float4*)&xs[row][q4 * 4] =
                        *(const float4*)(xz + ((size_t)qb * 384 + d0 + row) * Lq + l0 - 4 + q4 * 4);
            }
        }
    } else {
        #pragma unroll
        for (int it = 0; it < 4; it++) {
            int idx = it * 256 + tid;        // 1024 = 64 rows x 16 f4
            int row = idx >> 4, q4 = idx & 15;
            *(float4*)&xs[row][q4 * 4] =
                *(const float4*)(xz + ((size_t)qb * 384 + d0 + row) * Lq + l0 + q4 * 4);
        }
    }
    __syncthreads();
    int d = tid >> 2, lqi = tid & 3;
    float r[16];
    if (!isz) {
        int gd = q * DI + d0 + d;
        float w0 = cw[gd * 4 + 0], w1 = cw[gd * 4 + 1], w2 = cw[gd * 4 + 2], w3 = cw[gd * 4 + 3];
        float bias = cb[gd];
        #pragma unroll
        for (int i = 0; i < 16; i++) {
            int c = 4 + lqi * 16 + i;
            float a = bias + w0 * xs[d][c - 3] + w1 * xs[d][c - 2] + w2 * xs[d][c - 1] + w3 * xs[d][c];
            r[i] = a / (1.f + __expf(-a));
        }
    } else {
        #pragma unroll
        for (int i = 0; i < 16; i++) {
            float a = xs[d][lqi * 16 + i];
            r[i] = a / (1.f + __expf(-a));   // silu(z)
        }
    }
    __syncthreads();
    float* ts = &xs[0][0];                   // reuse as [64 d][65 l]
    #pragma unroll
    for (int i = 0; i < 16; i++) ts[d * 65 + lqi * 16 + i] = r[i];
    __syncthreads();
    int dz = tid & 63;
    float* dst = isz ? szt : xi;
    int dcol = isz ? d0 - 192 : d0;
    #pragma unroll
    for (int it = 0; it < 16; it++) {
        int l = it * 4 + (tid >> 6);
        dst[((size_t)qb * Lq + l0 + l) * DI + dcol + dz] = ts[dz * 65 + l];
    }
}

__device__ __forceinline__ float softplusf(float x) {
    return fmaxf(x, 0.f) + __logf(1.f + __expf(-fabsf(x)));
}

// ---------------- x-projection GEMM -> dbl[qb][l][40] + fused delta ---------
// dbl cols: 0..5 dt, 8..23 B, 24..39 C
__global__ void k_xpproj(const float* __restrict__ xi, const float* __restrict__ xp_w,
                         const float* __restrict__ dt_w, const float* __restrict__ dt_b,
                         float* __restrict__ dbl, float* __restrict__ delta) {
    __shared__ float xt[64][65];    // [l][k-chunk]
    __shared__ float wq[48][68];    // [j][k]
    __shared__ float dtile[64][44]; // [l][40-col repack]
    int lt = blockIdx.x, qb = blockIdx.y, q = qb >> 1;
    int tid = threadIdx.x, tx = tid & 15, ty = tid >> 4;
    int l0 = lt * 64;
    float acc[3][4] = {};
    for (int ks = 0; ks < 3; ks++) {
        __syncthreads();
        #pragma unroll
        for (int it = 0; it < 4; it++) {
            int idx = it * 256 + tid; int l = idx >> 4, kq = idx & 15;
            *(float4*)&xt[l][kq * 4] =
                *(const float4*)(xi + ((size_t)qb * Lq + l0 + l) * DI + ks * 64 + kq * 4);
        }
        #pragma unroll
        for (int it = 0; it < 3; it++) {
            int idx = it * 256 + tid;
            if (idx < 608) {
                int j = idx >> 4, kq = idx & 15;
                *(float4*)&wq[j][kq * 4] =
                    *(const float4*)(xp_w + ((size_t)q * 38 + j) * DI + ks * 64 + kq * 4);
            }
        }
        __syncthreads();
        #pragma unroll 8
        for (int k = 0; k < 64; k++) {
            float x0 = xt[tx * 4 + 0][k], x1 = xt[tx * 4 + 1][k];
            float x2 = xt[tx * 4 + 2][k], x3 = xt[tx * 4 + 3][k];
            float v0 = wq[ty][k], v1 = wq[ty + 16][k], v2 = wq[ty + 32][k];
            acc[0][0] += v0 * x0; acc[0][1] += v0 * x1; acc[0][2] += v0 * x2; acc[0][3] += v0 * x3;
            acc[1][0] += v1 * x0; acc[1][1] += v1 * x1; acc[1][2] += v1 * x2; acc[1][3] += v1 * x3;
            acc[2][0] += v2 * x0; acc[2][1] += v2 * x1; acc[2][2] += v2 * x2; acc[2][3] += v2 * x3;
        }
    }
    #pragma unroll
    for (int t = 0; t < 3; t++) {
        int j = ty + 16 * t;
        if (j < 38) {
            int col = j + (j >= 6 ? 2 : 0);
            #pragma unroll
            for (int i = 0; i < 4; i++) dtile[tx * 4 + i][col] = acc[t][i];
        }
    }
    __syncthreads();
    #pragma unroll
    for (int it = 0; it < 3; it++) {
        int idx = it * 256 + tid;            // 640 = 64 rows x 10 f4
        if (idx < 640) {
            int row = idx / 10, q4 = idx % 10;
            *(float4*)(dbl + ((size_t)qb * Lq + l0 + row) * 40 + q4 * 4) =
                *(float4*)&dtile[row][q4 * 4];
        }
    }
    if (tid < DI) {
        int d = tid;
        float dw[6];
        #pragma unroll
        for (int r = 0; r < 6; r++) dw[r] = dt_w[(size_t)(q * DI + d) * 6 + r];
        float db = dt_b[q * DI + d];
        for (int l = 0; l < 64; l++) {
            float t = db;
            #pragma unroll
            for (int r = 0; r < 6; r++) t += dtile[l][r] * dw[r];
            delta[((size_t)qb * Lq + l0 + l) * DI + d] = softplusf(t);
        }
    }
}

// ---------------- scan pass 1: per-chunk decay product + local state --------
__global__ void k_scan1(const float* __restrict__ dbl, const float* __restrict__ delta,
                        const float* __restrict__ xi, const float* __restrict__ A_log,
                        float* __restrict__ P, float* __restrict__ Hl) {
    int qb = blockIdx.y; int q = qb >> 1;
    int ch = blockIdx.x;
    int d = threadIdx.x;
    float A[16], h[16];
    #pragma unroll
    for (int s = 0; s < 16; s++) {
        A[s] = -__expf(A_log[((size_t)(q * DI + d)) * 16 + s]);
        h[s] = 0.f;
    }
    float desum = 0.f;
    size_t lbase = (size_t)qb * Lq + ch * CH;
    for (int i = 0; i < CH; i++) {
        size_t l = lbase + i;
        const float* row = dbl + l * 40;
        float de = delta[l * DI + d];
        float dx = de * xi[l * DI + d];
        desum += de;
        float Bv[16];
        *(float4*)&Bv[0]  = *(const float4*)(row + 8);
        *(float4*)&Bv[4]  = *(const float4*)(row + 12);
        *(float4*)&Bv[8]  = *(const float4*)(row + 16);
        *(float4*)&Bv[12] = *(const float4*)(row + 20);
        #pragma unroll
        for (int s = 0; s < 16; s++) {
            float dA = __expf(de * A[s]);
            h[s] = dA * h[s] + dx * Bv[s];
        }
    }
    size_t base = ((size_t)qb * NCH + ch) * 16;
    #pragma unroll
    for (int s = 0; s < 16; s++) {
        P[(base + s) * DI + d]  = __expf(desum * A[s]);   // prod exp(dA) = exp(A*sum_d)
        Hl[(base + s) * DI + d] = h[s];
    }
}

// ---------------- scan pass 2: serial recombination; carry written into P ---
__global__ void k_scan2(float* __restrict__ P, const float* __restrict__ Hl) {
    int t = blockIdx.x * 256 + threadIdx.x;   // qb*3072 + sd
    int qb = t / (16 * DI);
    int sd = t % (16 * DI);
    float c = 0.f;
    for (int ch = 0; ch < NCH; ch++) {
        size_t idx = (size_t)(qb * NCH + ch) * (16 * DI) + sd;
        float p = P[idx], hl = Hl[idx];
        P[idx] = c;                 // carry in
        c = p * c + hl;
    }
}

// ---------------- scan pass 3: seeded rerun + y + gate; y aliases delta -----
__global__ void k_scan3(const float* __restrict__ dbl, float* deltaY,
                        const float* __restrict__ xi, const float* __restrict__ szt,
                        const float* __restrict__ A_log, const float* __restrict__ Dp,
                        const float* __restrict__ carry) {
    int qb = blockIdx.y; int q = qb >> 1;
    int ch = blockIdx.x;
    int d = threadIdx.x;
    float A[16], h[16];
    size_t cbase = (size_t)(qb * NCH + ch) * (16 * DI) + d;
    #pragma unroll
    for (int s = 0; s < 16; s++) {
        A[s] = -__expf(A_log[((size_t)(q * DI + d)) * 16 + s]);
        h[s] = carry[cbase + (size_t)s * DI];
    }
    float dpv = Dp[q * DI + d];
    size_t lbase = (size_t)qb * Lq + ch * CH;
    for (int i = 0; i < CH; i++) {
        size_t l = lbase + i;
        const float* row = dbl + l * 40;
        float de = deltaY[l * DI + d];
        float xiv = xi[l * DI + d];
        float szv = szt[l * DI + d];
        float dx = de * xiv;
        float Bv[16], Cv[16];
        *(float4*)&Bv[0]  = *(const float4*)(row + 8);
        *(float4*)&Bv[4]  = *(const float4*)(row + 12);
        *(float4*)&Bv[8]  = *(const float4*)(row + 16);
        *(float4*)&Bv[12] = *(const float4*)(row + 20);
        *(float4*)&Cv[0]  = *(const float4*)(row + 24);
        *(float4*)&Cv[4]  = *(const float4*)(row + 28);
        *(float4*)&Cv[8]  = *(const float4*)(row + 32);
        *(float4*)&Cv[12] = *(const float4*)(row + 36);
        float y = 0.f;
        #pragma unroll
        for (int s = 0; s < 16; s++) {
            float dA = __expf(de * A[s]);
            h[s] = dA * h[s] + dx * Bv[s];
            y += h[s] * Cv[s];
        }
        y += xiv * dpv;
        y *= szv;                   // silu(z) precomputed
        deltaY[l * DI + d] = y;     // overwrite delta (read-before-write per element)
    }
}

// ---------------- out-projection (y[l][d]) + residual add into xd -----------
__global__ void k_outproj_t(const float* __restrict__ yg, const float* __restrict__ out_w,
                            float* __restrict__ xd) {
    __shared__ float Ys[48][65];    // [k][l]
    __shared__ float Ws2[48][52];   // [c][k]
    int lt = blockIdx.x;            // 64 l-tiles (quadrant row)
    int ct = blockIdx.y;            // 2 c-tiles of 48
    int qb = blockIdx.z; int q = qb >> 1, b = qb & 1;
    int qr = q >> 1, qc = q & 1;
    int tid = threadIdx.x, tx = tid & 15, ty = tid >> 4;
    int l0 = lt * 64;
    float acc[3][4] = {};
    for (int ks = 0; ks < 4; ks++) {
        __syncthreads();
        #pragma unroll
        for (int it = 0; it < 3; it++) {
            int idx = it * 256 + tid;       // 64 l x 12 kq = 768
            if (idx < 768) {
                int l = idx / 12, kq = idx % 12;
                float4 v = *(const float4*)(yg + ((size_t)qb * Lq + l0 + l) * DI + ks * 48 + kq * 4);
                Ys[kq * 4 + 0][l] = v.x; Ys[kq * 4 + 1][l] = v.y;
                Ys[kq * 4 + 2][l] = v.z; Ys[kq * 4 + 3][l] = v.w;
            }
        }
        #pragma unroll
        for (int it = 0; it < 3; it++) {
            int idx = it * 256 + tid;       // 48 c x 12 = 576
            if (idx < 576) {
                int row = idx / 12, q4 = idx % 12;
                float4 v = *(const float4*)(out_w + ((size_t)(q * Cc + ct * 48 + row)) * DI + ks * 48 + q4 * 4);
                *(float4*)&Ws2[row][q4 * 4] = v;
            }
        }
        __syncthreads();
        #pragma unroll 4
        for (int kk = 0; kk < 48; kk++) {
            float y0 = Ys[kk][tx * 4], y1 = Ys[kk][tx * 4 + 1], y2 = Ys[kk][tx * 4 + 2], y3 = Ys[kk][tx * 4 + 3];
            float w0 = Ws2[ty][kk], w1 = Ws2[ty + 16][kk], w2 = Ws2[ty + 32][kk];
            acc[0][0] += w0 * y0; acc[0][1] += w0 * y1; acc[0][2] += w0 * y2; acc[0][3] += w0 * y3;
            acc[1][0] += w1 * y0; acc[1][1] += w1 * y1; acc[1][2] += w1 * y2; acc[1][3] += w1 * y3;
            acc[2][0] += w2 * y0; acc[2][1] += w2 * y1; acc[2][2] += w2 * y2; acc[2][3] += w2 * y3;
        }
    }
    #pragma unroll
    for (int i = 0; i < 3; i++) {
        int c = ct * 48 + ty + 16 * i;
        float* p = xd + ((size_t)(b * Cc + c) * Hc + qr * 64 + lt) * Wcn + qc * 64 + tx * 4;
        float4 v = *(float4*)p;
        v.x += acc[i][0]; v.y += acc[i][1]; v.z += acc[i][2]; v.w += acc[i][3];
        *(float4*)p = v;
    }
}

extern "C" void kernel_launch(void* const* d_in, const int* in_sizes, int n_in,
                              void* d_out, int out_size, void* d_ws, size_t ws_size,
                              hipStream_t stream) {
    const float* x     = (const float*)d_in[0];
    const float* ln_w  = (const float*)d_in[1];
    const float* ln_b  = (const float*)d_in[2];
    const float* in_w  = (const float*)d_in[3];
    const float* cw    = (const float*)d_in[4];
    const float* cb    = (const float*)d_in[5];
    const float* xp_w  = (const float*)d_in[6];
    const float* dt_w  = (const float*)d_in[7];
    const float* dt_b  = (const float*)d_in[8];
    const float* A_log = (const float*)d_in[9];
    const float* Dp    = (const float*)d_in[10];
    const float* out_w = (const float*)d_in[11];
    float* out = (float*)d_out;

    float* ws = (float*)d_ws;
    const size_t NPIX = (size_t)Bc * Cc * Hc * Wcn;      // 3,145,728
    float* M     = ws;                    // 16384
    float* MT    = M + 16384;             // 16384
    float* keep  = MT + 16384;            // 32768
    float* tmpxn = keep + 32768;          // NPIX: DCT-tmp -> xn -> Hl -> iDCT-tmp
    float* xd    = tmpxn + NPIX;          // NPIX
    float* xz    = xd + NPIX;             // 4*NPIX = 8*384*4096  (aliased: P)
    float* xi    = xz + 4 * NPIX;         // 2*NPIX = 8*4096*192
    float* szt   = xi + 2 * NPIX;         // 2*NPIX
    float* dbl   = szt + 2 * NPIX;        // 8*4096*40
    float* delta = dbl + (size_t)8 * Lq * 40;   // 2*NPIX (aliased: y)
    float* P  = xz;                       // NPIX (8*128*16*192)
    float* Hl = tmpxn;                    // NPIX

    k_dct_mat<<<128, 128, 0, stream>>>(M, MT);
    k_mask2<<<dim3(Hc, Bc), Wcn, 0, stream>>>(x, keep);
    k_g128<<<dim3(192, 2), 256, 0, stream>>>(M, 0, x, 16384, tmpxn, keep);     // DCT rows (masked)
    k_g128<<<dim3(192, 2), 256, 0, stream>>>(tmpxn, 16384, MT, 0, xd, nullptr); // DCT cols
    k_ln_pack<<<dim3(Hc, Bc), Wcn, 0, stream>>>(xd, ln_w, ln_b, tmpxn);
    k_inproj_g<<<dim3(32, 6, 8), 256, 0, stream>>>(tmpxn, in_w, xz);
    k_conv<<<dim3(64, 6, 8), 256, 0, stream>>>(xz, cw, cb, xi, szt);
    k_xpproj<<<dim3(64, 8), 256, 0, stream>>>(xi, xp_w, dt_w, dt_b, dbl, delta);
    k_scan1<<<dim3(NCH, 8), DI, 0, stream>>>(dbl, delta, xi, A_log, P, Hl);
    k_scan2<<<96, 256, 0, stream>>>(P, Hl);
    k_scan3<<<dim3(NCH, 8), DI, 0, stream>>>(dbl, delta, xi, szt, A_log, Dp, P);
    k_outproj_t<<<dim3(64, 2, 8), 256, 0, stream>>>(delta, out_w, xd);
    k_g128<<<dim3(192, 2), 256, 0, stream>>>(xd, 16384, M, 0, tmpxn, nullptr); // iDCT cols
    k_g128<<<dim3(192, 2), 256, 0, stream>>>(MT, 0, tmpxn, 16384, out, nullptr); // iDCT rows
}

// Round 7
// 274.589 us; speedup vs baseline: 1.0523x; 1.0523x over previous
//
#include <hip/hip_runtime.h>
#include <math.h>

#define D_STATE 16
#define DT_RANK 6
constexpr int Bc = 2, Cc = 96, Hc = 128, Wcn = 128;
constexpr int DI = 192;       // d_inner
constexpr int Lq = 4096;      // 64*64 per quadrant
constexpr int CH = 32;        // scan chunk length
constexpr int NCH = Lq / CH;  // 128 chunks

// ---------------- DCT matrix build ------------------------------------------
__global__ void k_dct_mat(float* __restrict__ M, float* __restrict__ MT) {
    int i = blockIdx.x * blockDim.x + threadIdx.x; // 16384
    int n = i >> 7, k = i & 127;
    double v = cos(3.14159265358979323846 * (2.0 * k + 1.0) * n / 256.0) * sqrt(2.0 / 128.0);
    if (n == 0) v *= 0.70710678118654752440;
    M[n * 128 + k]  = (float)v;
    MT[k * 128 + n] = (float)v;
}

// ---------------- cosine-similarity mask: keep plane only -------------------
__global__ void k_mask2(const float* __restrict__ x, float* __restrict__ keep) {
    int b = blockIdx.y, h = blockIdx.x, w = threadIdx.x;
    const float* xb = x + (size_t)b * Cc * Hc * Wcn;
    float dot = 0.f, ss = 0.f, cs = 0.f;
    for (int c = 0; c < Cc; c++) {
        float xv = xb[(size_t)(c * Hc + h) * Wcn + w];
        float cv = xb[(size_t)(c * Hc + 64) * Wcn + 64];
        dot += xv * cv; ss += xv * xv; cs += cv * cv;
    }
    float sim = dot / (sqrtf(cs) * sqrtf(ss) + 1e-6f);
    keep[(size_t)b * 16384 + h * 128 + w] = (sim >= 0.7f) ? 1.0f : 0.0f;
}

// ---------------- tiled 128x128x128 GEMM (64x64 tile, proven shape) ---------
// D[bc,r,n] = sum_j L[r,j]·(mask? keep[b,j,n]*R[j,n] : R[j,n])
__global__ void k_g128(const float* __restrict__ L, size_t lb,
                       const float* __restrict__ R, size_t rb,
                       float* __restrict__ D, const float* __restrict__ mask) {
    __shared__ float Ls[64][68];
    __shared__ float Rs[64][68];
    int bc = blockIdx.x;
    int r0 = blockIdx.y * 64, n0 = blockIdx.z * 64;
    const float* Lp = L + lb * bc;
    const float* Rp = R + rb * bc;
    const float* mp = mask ? mask + (size_t)(bc / 96) * 16384 : nullptr;
    float* Dq = D + (size_t)bc * 16384;
    int tid = threadIdx.x, tx = tid & 15, ty = tid >> 4;
    float acc[4][4] = {};
    for (int ks = 0; ks < 2; ks++) {
        __syncthreads();
        #pragma unroll
        for (int i = 0; i < 4; i++) {
            int idx = i * 256 + tid;
            int row = idx >> 4, quad = idx & 15;
            *(float4*)&Ls[row][quad * 4] =
                *(const float4*)(Lp + (size_t)(r0 + row) * 128 + ks * 64 + quad * 4);
            float4 rv = *(const float4*)(Rp + (size_t)(ks * 64 + row) * 128 + n0 + quad * 4);
            if (mp) {
                float4 m4 = *(const float4*)(mp + (size_t)(ks * 64 + row) * 128 + n0 + quad * 4);
                rv.x *= m4.x; rv.y *= m4.y; rv.z *= m4.z; rv.w *= m4.w;
            }
            *(float4*)&Rs[row][quad * 4] = rv;
        }
        __syncthreads();
        #pragma unroll 8
        for (int j = 0; j < 64; j++) {
            float a0 = Ls[ty][j], a1 = Ls[ty + 16][j], a2 = Ls[ty + 32][j], a3 = Ls[ty + 48][j];
            float4 bv = *(float4*)&Rs[j][tx * 4];
            acc[0][0] += a0 * bv.x; acc[0][1] += a0 * bv.y; acc[0][2] += a0 * bv.z; acc[0][3] += a0 * bv.w;
            acc[1][0] += a1 * bv.x; acc[1][1] += a1 * bv.y; acc[1][2] += a1 * bv.z; acc[1][3] += a1 * bv.w;
            acc[2][0] += a2 * bv.x; acc[2][1] += a2 * bv.y; acc[2][2] += a2 * bv.z; acc[2][3] += a2 * bv.w;
            acc[3][0] += a3 * bv.x; acc[3][1] += a3 * bv.y; acc[3][2] += a3 * bv.z; acc[3][3] += a3 * bv.w;
        }
    }
    #pragma unroll
    for (int i = 0; i < 4; i++) {
        *(float4*)(Dq + (size_t)(r0 + ty + 16 * i) * 128 + n0 + tx * 4) =
            make_float4(acc[i][0], acc[i][1], acc[i][2], acc[i][3]);
    }
}

// ---------------- LN stats: mu/inv planes over channels ---------------------
__global__ void k_ln_stats(const float* __restrict__ xd, float* __restrict__ mu_p,
                           float* __restrict__ inv_p) {
    __shared__ float rs[4][64], rq[4][64];
    int p0 = blockIdx.x * 64;            // 512 blocks cover 32768 pixels
    int l = threadIdx.x & 63, g = threadIdx.x >> 6;
    int p = p0 + l;
    int b = p >> 14, hw = p & 16383;
    const float* src = xd + (size_t)b * Cc * 16384 + hw;
    float s = 0.f, sq = 0.f;
    #pragma unroll
    for (int c = 0; c < 24; c++) {
        float v = src[(size_t)(g * 24 + c) * 16384];
        s += v; sq += v * v;
    }
    rs[g][l] = s; rq[g][l] = sq;
    __syncthreads();
    if (threadIdx.x < 64) {
        float S = rs[0][l] + rs[1][l] + rs[2][l] + rs[3][l];
        float Q = rq[0][l] + rq[1][l] + rq[2][l] + rq[3][l];
        float mu = S * (1.f / 96.f);
        float var = Q * (1.f / 96.f) - mu * mu;
        mu_p[p0 + l] = mu;
        inv_p[p0 + l] = rsqrtf(var + 1e-5f);
    }
}

// ---------------- in-projection GEMM with LN fused at staging ---------------
// xz[qb][e][l], e in [0,384);  X staged from xd directly (quadrant indexing).
__global__ void k_inproj_g(const float* __restrict__ xd, const float* __restrict__ mu_p,
                           const float* __restrict__ inv_p, const float* __restrict__ lnw,
                           const float* __restrict__ lnb, const float* __restrict__ in_w,
                           float* __restrict__ xz) {
    __shared__ float Ws[64][52];     // [e][k-chunk 48]
    __shared__ float Xs[48][132];    // [k][l-tile 128]
    __shared__ float lws[96], lbs[96];
    int lt = blockIdx.x, et = blockIdx.y, qb = blockIdx.z;
    int q = qb >> 1, b = qb & 1;
    int qr = q >> 1, qc = q & 1;
    int tid = threadIdx.x, tx = tid & 15, ty = tid >> 4;
    int l0 = lt * 128;
    int hh0 = l0 >> 6;               // first quadrant row of this tile (2 rows)
    if (tid < 96) { lws[tid] = lnw[tid]; lbs[tid] = lnb[tid]; }
    size_t baseX = (((size_t)b * Cc) * 128 + qr * 64 + hh0) * 128 + qc * 64;
    size_t baseM = ((size_t)b * 128 + qr * 64 + hh0) * 128 + qc * 64;
    float acc[4][8] = {};
    for (int ks = 0; ks < 2; ks++) {
        __syncthreads();
        #pragma unroll
        for (int i = 0; i < 3; i++) {
            int idx = i * 256 + tid;         // 768 = 64 rows x 12 f4
            int row = idx / 12, q4 = idx % 12;
            *(float4*)&Ws[row][q4 * 4] =
                *(const float4*)(in_w + ((size_t)(q * 384 + et * 64 + row)) * 96 + ks * 48 + q4 * 4);
        }
        #pragma unroll
        for (int i = 0; i < 6; i++) {
            int idx = i * 256 + tid;         // 1536 = 48 rows x 32 f4
            int row = idx >> 5, quad = idx & 31;
            int lh = quad >> 4;              // 0/1: which h-row
            int lw4 = (quad & 15) * 4;
            int c = ks * 48 + row;
            float4 v = *(const float4*)(xd + baseX + (size_t)c * 16384 + lh * 128 + lw4);
            float4 m = *(const float4*)(mu_p + baseM + lh * 128 + lw4);
            float4 iv = *(const float4*)(inv_p + baseM + lh * 128 + lw4);
            float wc = lws[c], bc2 = lbs[c];
            v.x = (v.x - m.x) * iv.x * wc + bc2;
            v.y = (v.y - m.y) * iv.y * wc + bc2;
            v.z = (v.z - m.z) * iv.z * wc + bc2;
            v.w = (v.w - m.w) * iv.w * wc + bc2;
            *(float4*)&Xs[row][quad * 4] = v;
        }
        __syncthreads();
        #pragma unroll 4
        for (int k = 0; k < 48; k++) {
            float a0 = Ws[ty][k], a1 = Ws[ty + 16][k], a2 = Ws[ty + 32][k], a3 = Ws[ty + 48][k];
            float4 b0 = *(float4*)&Xs[k][tx * 4];
            float4 b1 = *(float4*)&Xs[k][64 + tx * 4];
            acc[0][0] += a0 * b0.x; acc[0][1] += a0 * b0.y; acc[0][2] += a0 * b0.z; acc[0][3] += a0 * b0.w;
            acc[0][4] += a0 * b1.x; acc[0][5] += a0 * b1.y; acc[0][6] += a0 * b1.z; acc[0][7] += a0 * b1.w;
            acc[1][0] += a1 * b0.x; acc[1][1] += a1 * b0.y; acc[1][2] += a1 * b0.z; acc[1][3] += a1 * b0.w;
            acc[1][4] += a1 * b1.x; acc[1][5] += a1 * b1.y; acc[1][6] += a1 * b1.z; acc[1][7] += a1 * b1.w;
            acc[2][0] += a2 * b0.x; acc[2][1] += a2 * b0.y; acc[2][2] += a2 * b0.z; acc[2][3] += a2 * b0.w;
            acc[2][4] += a2 * b1.x; acc[2][5] += a2 * b1.y; acc[2][6] += a2 * b1.z; acc[2][7] += a2 * b1.w;
            acc[3][0] += a3 * b0.x; acc[3][1] += a3 * b0.y; acc[3][2] += a3 * b0.z; acc[3][3] += a3 * b0.w;
            acc[3][4] += a3 * b1.x; acc[3][5] += a3 * b1.y; acc[3][6] += a3 * b1.z; acc[3][7] += a3 * b1.w;
        }
    }
    #pragma unroll
    for (int i = 0; i < 4; i++) {
        size_t rb2 = ((size_t)qb * 384 + et * 64 + ty + 16 * i) * Lq + l0;
        *(float4*)(xz + rb2 + tx * 4) = make_float4(acc[i][0], acc[i][1], acc[i][2], acc[i][3]);
        *(float4*)(xz + rb2 + 64 + tx * 4) = make_float4(acc[i][4], acc[i][5], acc[i][6], acc[i][7]);
    }
}

// ---------------- conv/silu (d<192) or silu(z) (d>=192); transpose to [l][d]
__global__ void k_conv(const float* __restrict__ xz, const float* __restrict__ cw,
                       const float* __restrict__ cb, float* __restrict__ xi,
                       float* __restrict__ szt) {
    __shared__ float xs[64][68];
    int lt = blockIdx.x, dt = blockIdx.y;
    int qb = blockIdx.z, q = qb >> 1;
    int tid = threadIdx.x;
    int l0 = lt * 64, d0 = dt * 64;
    bool isz = dt >= 3;
    if (!isz) {
        #pragma unroll
        for (int it = 0; it < 5; it++) {
            int idx = it * 256 + tid;        // 1088 = 64 rows x 17 f4 (4-col halo)
            if (idx < 1088) {
                int row = idx / 17, q4 = idx % 17;
                if (l0 == 0 && q4 == 0)
                    *(float4*)&xs[row][0] = make_float4(0.f, 0.f, 0.f, 0.f);
                else
                    *(float4*)&xs[row][q4 * 4] =
                        *(const float4*)(xz + ((size_t)qb * 384 + d0 + row) * Lq + l0 - 4 + q4 * 4);
            }
        }
    } else {
        #pragma unroll
        for (int it = 0; it < 4; it++) {
            int idx = it * 256 + tid;        // 1024 = 64 rows x 16 f4
            int row = idx >> 4, q4 = idx & 15;
            *(float4*)&xs[row][q4 * 4] =
                *(const float4*)(xz + ((size_t)qb * 384 + d0 + row) * Lq + l0 + q4 * 4);
        }
    }
    __syncthreads();
    int d = tid >> 2, lqi = tid & 3;
    float r[16];
    if (!isz) {
        int gd = q * DI + d0 + d;
        float w0 = cw[gd * 4 + 0], w1 = cw[gd * 4 + 1], w2 = cw[gd * 4 + 2], w3 = cw[gd * 4 + 3];
        float bias = cb[gd];
        #pragma unroll
        for (int i = 0; i < 16; i++) {
            int c = 4 + lqi * 16 + i;
            float a = bias + w0 * xs[d][c - 3] + w1 * xs[d][c - 2] + w2 * xs[d][c - 1] + w3 * xs[d][c];
            r[i] = a / (1.f + __expf(-a));
        }
    } else {
        #pragma unroll
        for (int i = 0; i < 16; i++) {
            float a = xs[d][lqi * 16 + i];
            r[i] = a / (1.f + __expf(-a));   // silu(z)
        }
    }
    __syncthreads();
    float* ts = &xs[0][0];                   // reuse as [64 d][65 l]
    #pragma unroll
    for (int i = 0; i < 16; i++) ts[d * 65 + lqi * 16 + i] = r[i];
    __syncthreads();
    int dz = tid & 63;
    float* dst = isz ? szt : xi;
    int dcol = isz ? d0 - 192 : d0;
    #pragma unroll
    for (int it = 0; it < 16; it++) {
        int l = it * 4 + (tid >> 6);
        dst[((size_t)qb * Lq + l0 + l) * DI + dcol + dz] = ts[dz * 65 + l];
    }
}

__device__ __forceinline__ float softplusf(float x) {
    return fmaxf(x, 0.f) + __logf(1.f + __expf(-fabsf(x)));
}

// ---------------- x-projection GEMM -> dbl[qb][l][40] + fused delta ---------
// dbl cols: 0..5 dt, 8..23 B, 24..39 C
__global__ void k_xpproj(const float* __restrict__ xi, const float* __restrict__ xp_w,
                         const float* __restrict__ dt_w, const float* __restrict__ dt_b,
                         float* __restrict__ dbl, float* __restrict__ delta) {
    __shared__ float xt[64][65];    // [l][k-chunk]
    __shared__ float wq[48][68];    // [j][k]
    __shared__ float dtile[64][44]; // [l][40-col repack]
    int lt = blockIdx.x, qb = blockIdx.y, q = qb >> 1;
    int tid = threadIdx.x, tx = tid & 15, ty = tid >> 4;
    int l0 = lt * 64;
    float acc[3][4] = {};
    for (int ks = 0; ks < 3; ks++) {
        __syncthreads();
        #pragma unroll
        for (int it = 0; it < 4; it++) {
            int idx = it * 256 + tid; int l = idx >> 4, kq = idx & 15;
            *(float4*)&xt[l][kq * 4] =
                *(const float4*)(xi + ((size_t)qb * Lq + l0 + l) * DI + ks * 64 + kq * 4);
        }
        #pragma unroll
        for (int it = 0; it < 3; it++) {
            int idx = it * 256 + tid;
            if (idx < 608) {
                int j = idx >> 4, kq = idx & 15;
                *(float4*)&wq[j][kq * 4] =
                    *(const float4*)(xp_w + ((size_t)q * 38 + j) * DI + ks * 64 + kq * 4);
            }
        }
        __syncthreads();
        #pragma unroll 8
        for (int k = 0; k < 64; k++) {
            float x0 = xt[tx * 4 + 0][k], x1 = xt[tx * 4 + 1][k];
            float x2 = xt[tx * 4 + 2][k], x3 = xt[tx * 4 + 3][k];
            float v0 = wq[ty][k], v1 = wq[ty + 16][k], v2 = wq[ty + 32][k];
            acc[0][0] += v0 * x0; acc[0][1] += v0 * x1; acc[0][2] += v0 * x2; acc[0][3] += v0 * x3;
            acc[1][0] += v1 * x0; acc[1][1] += v1 * x1; acc[1][2] += v1 * x2; acc[1][3] += v1 * x3;
            acc[2][0] += v2 * x0; acc[2][1] += v2 * x1; acc[2][2] += v2 * x2; acc[2][3] += v2 * x3;
        }
    }
    #pragma unroll
    for (int t = 0; t < 3; t++) {
        int j = ty + 16 * t;
        if (j < 38) {
            int col = j + (j >= 6 ? 2 : 0);
            #pragma unroll
            for (int i = 0; i < 4; i++) dtile[tx * 4 + i][col] = acc[t][i];
        }
    }
    __syncthreads();
    #pragma unroll
    for (int it = 0; it < 3; it++) {
        int idx = it * 256 + tid;            // 640 = 64 rows x 10 f4
        if (idx < 640) {
            int row = idx / 10, q4 = idx % 10;
            *(float4*)(dbl + ((size_t)qb * Lq + l0 + row) * 40 + q4 * 4) =
                *(float4*)&dtile[row][q4 * 4];
        }
    }
    if (tid < DI) {
        int d = tid;
        float dw[6];
        #pragma unroll
        for (int r = 0; r < 6; r++) dw[r] = dt_w[(size_t)(q * DI + d) * 6 + r];
        float db = dt_b[q * DI + d];
        for (int l = 0; l < 64; l++) {
            float t = db;
            #pragma unroll
            for (int r = 0; r < 6; r++) t += dtile[l][r] * dw[r];
            delta[((size_t)qb * Lq + l0 + l) * DI + d] = softplusf(t);
        }
    }
}

// ---------------- scan pass 1: per-chunk decay product + local state --------
__global__ void k_scan1(const float* __restrict__ dbl, const float* __restrict__ delta,
                        const float* __restrict__ xi, const float* __restrict__ A_log,
                        float* __restrict__ P, float* __restrict__ Hl) {
    int qb = blockIdx.y; int q = qb >> 1;
    int ch = blockIdx.x;
    int d = threadIdx.x;
    float A[16], h[16];
    #pragma unroll
    for (int s = 0; s < 16; s++) {
        A[s] = -__expf(A_log[((size_t)(q * DI + d)) * 16 + s]);
        h[s] = 0.f;
    }
    float desum = 0.f;
    size_t lbase = (size_t)qb * Lq + ch * CH;
    for (int i = 0; i < CH; i++) {
        size_t l = lbase + i;
        const float* row = dbl + l * 40;
        float de = delta[l * DI + d];
        float dx = de * xi[l * DI + d];
        desum += de;
        float Bv[16];
        *(float4*)&Bv[0]  = *(const float4*)(row + 8);
        *(float4*)&Bv[4]  = *(const float4*)(row + 12);
        *(float4*)&Bv[8]  = *(const float4*)(row + 16);
        *(float4*)&Bv[12] = *(const float4*)(row + 20);
        #pragma unroll
        for (int s = 0; s < 16; s++) {
            float dA = __expf(de * A[s]);
            h[s] = dA * h[s] + dx * Bv[s];
        }
    }
    size_t base = ((size_t)qb * NCH + ch) * 16;
    #pragma unroll
    for (int s = 0; s < 16; s++) {
        P[(base + s) * DI + d]  = __expf(desum * A[s]);   // prod exp(dA) = exp(A*sum_d)
        Hl[(base + s) * DI + d] = h[s];
    }
}

// ---------------- scan pass 2: serial recombination; carry written into P ---
__global__ void k_scan2(float* __restrict__ P, const float* __restrict__ Hl) {
    int t = blockIdx.x * 256 + threadIdx.x;   // qb*3072 + sd
    int qb = t / (16 * DI);
    int sd = t % (16 * DI);
    float c = 0.f;
    for (int ch = 0; ch < NCH; ch++) {
        size_t idx = (size_t)(qb * NCH + ch) * (16 * DI) + sd;
        float p = P[idx], hl = Hl[idx];
        P[idx] = c;                 // carry in
        c = p * c + hl;
    }
}

// ---------------- scan pass 3: seeded rerun + y + gate; y aliases delta -----
__global__ void k_scan3(const float* __restrict__ dbl, float* deltaY,
                        const float* __restrict__ xi, const float* __restrict__ szt,
                        const float* __restrict__ A_log, const float* __restrict__ Dp,
                        const float* __restrict__ carry) {
    int qb = blockIdx.y; int q = qb >> 1;
    int ch = blockIdx.x;
    int d = threadIdx.x;
    float A[16], h[16];
    size_t cbase = (size_t)(qb * NCH + ch) * (16 * DI) + d;
    #pragma unroll
    for (int s = 0; s < 16; s++) {
        A[s] = -__expf(A_log[((size_t)(q * DI + d)) * 16 + s]);
        h[s] = carry[cbase + (size_t)s * DI];
    }
    float dpv = Dp[q * DI + d];
    size_t lbase = (size_t)qb * Lq + ch * CH;
    for (int i = 0; i < CH; i++) {
        size_t l = lbase + i;
        const float* row = dbl + l * 40;
        float de = deltaY[l * DI + d];
        float xiv = xi[l * DI + d];
        float szv = szt[l * DI + d];
        float dx = de * xiv;
        float Bv[16], Cv[16];
        *(float4*)&Bv[0]  = *(const float4*)(row + 8);
        *(float4*)&Bv[4]  = *(const float4*)(row + 12);
        *(float4*)&Bv[8]  = *(const float4*)(row + 16);
        *(float4*)&Bv[12] = *(const float4*)(row + 20);
        *(float4*)&Cv[0]  = *(const float4*)(row + 24);
        *(float4*)&Cv[4]  = *(const float4*)(row + 28);
        *(float4*)&Cv[8]  = *(const float4*)(row + 32);
        *(float4*)&Cv[12] = *(const float4*)(row + 36);
        float y = 0.f;
        #pragma unroll
        for (int s = 0; s < 16; s++) {
            float dA = __expf(de * A[s]);
            h[s] = dA * h[s] + dx * Bv[s];
            y += h[s] * Cv[s];
        }
        y += xiv * dpv;
        y *= szv;                   // silu(z) precomputed
        deltaY[l * DI + d] = y;     // overwrite delta (read-before-write per element)
    }
}

// ---------------- out-projection (y[l][d]) + residual add into xd -----------
__global__ void k_outproj_t(const float* __restrict__ yg, const float* __restrict__ out_w,
                            float* __restrict__ xd) {
    __shared__ float Ys[48][65];    // [k][l]
    __shared__ float Ws2[48][52];   // [c][k]
    int lt = blockIdx.x;            // 64 l-tiles (quadrant row)
    int ct = blockIdx.y;            // 2 c-tiles of 48
    int qb = blockIdx.z; int q = qb >> 1, b = qb & 1;
    int qr = q >> 1, qc = q & 1;
    int tid = threadIdx.x, tx = tid & 15, ty = tid >> 4;
    int l0 = lt * 64;
    float acc[3][4] = {};
    for (int ks = 0; ks < 4; ks++) {
        __syncthreads();
        #pragma unroll
        for (int it = 0; it < 3; it++) {
            int idx = it * 256 + tid;       // 64 l x 12 kq = 768
            if (idx < 768) {
                int l = idx / 12, kq = idx % 12;
                float4 v = *(const float4*)(yg + ((size_t)qb * Lq + l0 + l) * DI + ks * 48 + kq * 4);
                Ys[kq * 4 + 0][l] = v.x; Ys[kq * 4 + 1][l] = v.y;
                Ys[kq * 4 + 2][l] = v.z; Ys[kq * 4 + 3][l] = v.w;
            }
        }
        #pragma unroll
        for (int it = 0; it < 3; it++) {
            int idx = it * 256 + tid;       // 48 c x 12 = 576
            if (idx < 576) {
                int row = idx / 12, q4 = idx % 12;
                float4 v = *(const float4*)(out_w + ((size_t)(q * Cc + ct * 48 + row)) * DI + ks * 48 + q4 * 4);
                *(float4*)&Ws2[row][q4 * 4] = v;
            }
        }
        __syncthreads();
        #pragma unroll 4
        for (int kk = 0; kk < 48; kk++) {
            float y0 = Ys[kk][tx * 4], y1 = Ys[kk][tx * 4 + 1], y2 = Ys[kk][tx * 4 + 2], y3 = Ys[kk][tx * 4 + 3];
            float w0 = Ws2[ty][kk], w1 = Ws2[ty + 16][kk], w2 = Ws2[ty + 32][kk];
            acc[0][0] += w0 * y0; acc[0][1] += w0 * y1; acc[0][2] += w0 * y2; acc[0][3] += w0 * y3;
            acc[1][0] += w1 * y0; acc[1][1] += w1 * y1; acc[1][2] += w1 * y2; acc[1][3] += w1 * y3;
            acc[2][0] += w2 * y0; acc[2][1] += w2 * y1; acc[2][2] += w2 * y2; acc[2][3] += w2 * y3;
        }
    }
    #pragma unroll
    for (int i = 0; i < 3; i++) {
        int c = ct * 48 + ty + 16 * i;
        float* p = xd + ((size_t)(b * Cc + c) * Hc + qr * 64 + lt) * Wcn + qc * 64 + tx * 4;
        float4 v = *(float4*)p;
        v.x += acc[i][0]; v.y += acc[i][1]; v.z += acc[i][2]; v.w += acc[i][3];
        *(float4*)p = v;
    }
}

extern "C" void kernel_launch(void* const* d_in, const int* in_sizes, int n_in,
                              void* d_out, int out_size, void* d_ws, size_t ws_size,
                              hipStream_t stream) {
    const float* x     = (const float*)d_in[0];
    const float* ln_w  = (const float*)d_in[1];
    const float* ln_b  = (const float*)d_in[2];
    const float* in_w  = (const float*)d_in[3];
    const float* cw    = (const float*)d_in[4];
    const float* cb    = (const float*)d_in[5];
    const float* xp_w  = (const float*)d_in[6];
    const float* dt_w  = (const float*)d_in[7];
    const float* dt_b  = (const float*)d_in[8];
    const float* A_log = (const float*)d_in[9];
    const float* Dp    = (const float*)d_in[10];
    const float* out_w = (const float*)d_in[11];
    float* out = (float*)d_out;

    float* ws = (float*)d_ws;
    const size_t NPIX = (size_t)Bc * Cc * Hc * Wcn;      // 3,145,728
    float* M     = ws;                    // 16384
    float* MT    = M + 16384;             // 16384
    float* keep  = MT + 16384;            // 32768
    float* mu_p  = keep + 32768;          // 32768
    float* inv_p = mu_p + 32768;          // 32768
    float* tmpxn = inv_p + 32768;         // NPIX: DCT-tmp -> Hl -> iDCT-tmp
    float* xd    = tmpxn + NPIX;          // NPIX
    float* xz    = xd + NPIX;             // 4*NPIX = 8*384*4096  (aliased: P)
    float* xi    = xz + 4 * NPIX;         // 2*NPIX = 8*4096*192
    float* szt   = xi + 2 * NPIX;         // 2*NPIX
    float* dbl   = szt + 2 * NPIX;        // 8*4096*40
    float* delta = dbl + (size_t)8 * Lq * 40;   // 2*NPIX (aliased: y)
    float* P  = xz;                       // NPIX (8*128*16*192)
    float* Hl = tmpxn;                    // NPIX

    k_dct_mat<<<128, 128, 0, stream>>>(M, MT);
    k_mask2<<<dim3(Hc, Bc), Wcn, 0, stream>>>(x, keep);
    k_g128<<<dim3(192, 2, 2), 256, 0, stream>>>(M, 0, x, 16384, tmpxn, keep);      // DCT rows (masked)
    k_g128<<<dim3(192, 2, 2), 256, 0, stream>>>(tmpxn, 16384, MT, 0, xd, nullptr); // DCT cols
    k_ln_stats<<<512, 256, 0, stream>>>(xd, mu_p, inv_p);
    k_inproj_g<<<dim3(32, 6, 8), 256, 0, stream>>>(xd, mu_p, inv_p, ln_w, ln_b, in_w, xz);
    k_conv<<<dim3(64, 6, 8), 256, 0, stream>>>(xz, cw, cb, xi, szt);
    k_xpproj<<<dim3(64, 8), 256, 0, stream>>>(xi, xp_w, dt_w, dt_b, dbl, delta);
    k_scan1<<<dim3(NCH, 8), DI, 0, stream>>>(dbl, delta, xi, A_log, P, Hl);
    k_scan2<<<96, 256, 0, stream>>>(P, Hl);
    k_scan3<<<dim3(NCH, 8), DI, 0, stream>>>(dbl, delta, xi, szt, A_log, Dp, P);
    k_outproj_t<<<dim3(64, 2, 8), 256, 0, stream>>>(delta, out_w, xd);
    k_g128<<<dim3(192, 2, 2), 256, 0, stream>>>(xd, 16384, M, 0, tmpxn, nullptr);  // iDCT cols
    k_g128<<<dim3(192, 2, 2), 256, 0, stream>>>(MT, 0, tmpxn, 16384, out, nullptr); // iDCT rows
}